// Round 5
// baseline (17.026 us; speedup 1.0000x reference)
//
#include <hip/hip_runtime.h>
#include <hip/hip_bf16.h>

// IdentityEmbedding: projection is the constant [I_1024; 0], so
//   out[row, j] = (idx[row] == j && idx[row] < 1024) ? 1.0f : 0.0f
//
// Round-5 structure: two-phase.
//   1. hipMemsetAsync(d_out, 0, 64 MiB)  -- the runtime fill kernel runs at
//      ~7.1 TB/s (measured on this box via the harness's own 804 MB resets).
//   2. scatter kernel: one thread per row writes the single 1.0f for rows
//      with idx < 1024 (~330 of 16384 rows; the rest stay all-zero).
// Phase 2 traffic: 64 KiB idx read + <=64 KiB scattered dword writes.

__global__ void __launch_bounds__(256)
IdentityEmbedding_scatter_ones(
    const int* __restrict__ idx,
    float* __restrict__ out,
    int nrows) {
    const int i = blockIdx.x * blockDim.x + threadIdx.x;
    if (i < nrows) {
        const int iv = idx[i];
        if (iv < 1024) {
            out[(size_t)i * 1024 + iv] = 1.0f;
        }
    }
}

extern "C" void kernel_launch(void* const* d_in, const int* in_sizes, int n_in,
                              void* d_out, int out_size, void* d_ws, size_t ws_size,
                              hipStream_t stream) {
    const int* idx = (const int*)d_in[0];   // (B*T,) int32
    float*     out = (float*)d_out;         // (B*T, N_EMBD) f32
    const int nrows = in_sizes[0];          // 16384

    // Phase 1: zero the whole output (64 MiB) with the runtime fill kernel.
    hipMemsetAsync(d_out, 0, (size_t)out_size * sizeof(float), stream);

    // Phase 2: scatter the ones.
    const int threads = 256;
    const int blocks  = (nrows + threads - 1) / threads;  // 64
    IdentityEmbedding_scatter_ones<<<blocks, threads, 0, stream>>>(idx, out, nrows);
}

// Round 6
// 15.117 us; speedup vs baseline: 1.1263x; 1.1263x over previous
//
#include <hip/hip_runtime.h>
#include <hip/hip_bf16.h>

// IdentityEmbedding: projection is the constant [I_1024; 0], so
//   out[row, j] = (idx[row] == j && idx[row] < 1024) ? 1.0f : 0.0f
// Pure 64 MiB streaming write (+ 64 KiB idx read).
//
// Round-6: deconfound round 3. Plain (cached) stores — round 4 showed
// nontemporal cost ~0.8 µs — combined with 8 rows per block: 2048 blocks
// (8/CU), each thread issues 8 independent float4 stores (64 B/thread).
// Tests whether CP dispatch ramp for 16384 tiny workgroups is part of the
// ~6 µs fixed overhead.

typedef float f32x4 __attribute__((ext_vector_type(4)));

constexpr int ROWS_PER_BLOCK = 8;

__global__ void __launch_bounds__(256)
IdentityEmbedding_14147622273767_kernel(
    const int* __restrict__ idx,
    float* __restrict__ out) {
    const int t    = threadIdx.x;                      // 0 .. 255
    const int row0 = blockIdx.x * ROWS_PER_BLOCK;      // 0, 8, 16, ...

    // Block-uniform scalar loads of the 8 row indices.
    int iv[ROWS_PER_BLOCK];
#pragma unroll
    for (int r = 0; r < ROWS_PER_BLOCK; ++r) iv[r] = idx[row0 + r];

#pragma unroll
    for (int r = 0; r < ROWS_PER_BLOCK; ++r) {
        f32x4 v = {0.0f, 0.0f, 0.0f, 0.0f};
        if ((iv[r] >> 2) == t) {                       // implies iv < 1024
            v[iv[r] & 3] = 1.0f;
        }
        f32x4* __restrict__ dst =
            reinterpret_cast<f32x4*>(out + (size_t)(row0 + r) * 1024);
        dst[t] = v;
    }
}

extern "C" void kernel_launch(void* const* d_in, const int* in_sizes, int n_in,
                              void* d_out, int out_size, void* d_ws, size_t ws_size,
                              hipStream_t stream) {
    const int* idx = (const int*)d_in[0];   // (B*T,) int32
    float*     out = (float*)d_out;         // (B*T, N_EMBD) f32
    const int nrows   = in_sizes[0];        // 16384
    const int nblocks = nrows / ROWS_PER_BLOCK;  // 2048
    IdentityEmbedding_14147622273767_kernel<<<nblocks, 256, 0, stream>>>(idx, out);
}